// Round 17
// baseline (123.197 us; speedup 1.0000x reference)
//
#include <hip/hip_runtime.h>

// Conv2d 3x3 VALID (NCHW/OIHW, fp32), fp16 MFMA, v11 "row-granular steps".
// One step = one kernel ROW (kh): the 3 shifts kw=0,1,2 for an sp-pair need
// X cols ow..ow+3 = ONE float4 per channel. 3 steps (was 9): per step
// 8 float4 gathers/thread -> cvt -> 3 shift-slots in one LDS buffer ->
// sync -> 24 MFMA/wave -> sync. Gather VMEM 72->24 instrs/thread, syncs 9->5.
// Single 55KB buffer (3 slots), 2 blocks/CU. v7-verified mappings; accumulation
// order unchanged (shift 0..8) -> bit-identical output.

typedef __attribute__((ext_vector_type(8)))  _Float16 f16x8;
typedef __attribute__((ext_vector_type(16))) float    f32x16;

struct __attribute__((aligned(8))) f4u { float v[4]; };  // 8B-aligned 4-float load

constexpr int C_IN = 64, H = 112, W = 112;
constexpr int COUT = 128, OH = 110, OW = 110;
constexpr int NIMG = 32;
constexpr int KTOT = C_IN * 9;            // 576
constexpr int OSP  = OH * OW;             // 12100
constexpr int SPTOT = NIMG * OSP;         // 387200 = 3025*128
constexpr int IMG_STRIDE = C_IN * H * W;
constexpr int CH_STRIDE  = H * W;         // 12544
constexpr int LDC = 72;                   // hw per sp-row (144B, 16B-aligned)

__device__ __forceinline__ uint pkrtz_u32(float lo, float hi) {
    union { __fp16 __attribute__((ext_vector_type(2))) h; uint u; } c;
    c.h = __builtin_amdgcn_cvt_pkrtz(lo, hi);
    return c.u;
}

// column-swizzled LDS halfword index (in-row bijective, bank-balanced)
__device__ __forceinline__ int swz(int row, int chw) {
    return row * LDC + (chw ^ (((row >> 1) & 7) << 3));
}

// A16[((s*8+o)*COUT + cout)*8 + j] = (f16)Kw[cout][(o*8+j)*9 + s]  (v4-verified)
__global__ void prep_a(const float* __restrict__ Kw, _Float16* __restrict__ A16) {
    int idx = blockIdx.x * 256 + threadIdx.x;
    if (idx >= COUT * KTOT) return;
    int cout = idx / KTOT, k = idx - cout * KTOT;
    int c = k / 9, s = k - c * 9;
    int o = c >> 3, j = c & 7;
    A16[((size_t)(s * 8 + o) * COUT + cout) * 8 + j] = (_Float16)Kw[idx];
}

__global__ __launch_bounds__(512, 4)
void conv_v11(const float* __restrict__ X,
              const _Float16* __restrict__ A16,
              float* __restrict__ Out)
{
    __shared__ __align__(16) _Float16 Bs[3][128 * LDC];   // 55296 B, single-buffered

    const int t = threadIdx.x;

    // XCD-bijective block swizzle (m204); nwg=3025
    const int nwg = gridDim.x;
    const int q8 = nwg >> 3, r8 = nwg & 7;
    const int xcd = blockIdx.x & 7, idx8 = blockIdx.x >> 3;
    const int bid = (xcd < r8 ? xcd * (q8 + 1) : r8 * (q8 + 1) + (xcd - r8) * q8) + idx8;
    const int spBase = bid * 128;

    // ---- staging mapping (v4-identical): spp = sp-pair, c0 = 8-channel group ----
    const int spp = t & 63;
    const int c0  = (t >> 6) << 3;
    const int sp0 = spBase + 2 * spp;
    const int nimg = sp0 / OSP;
    const int rsp  = sp0 - nimg * OSP;
    const int oh   = rsp / OW;
    const int ow   = rsp - oh * OW;          // even; ow+3 <= 111 (in-row) always
    const float* Xr = X + ((size_t)nimg * IMG_STRIDE + (size_t)c0 * CH_STRIDE + oh * W + ow);
    const int whw0 = swz(2 * spp,     c0);
    const int whw1 = swz(2 * spp + 1, c0);

    // ---- compute mapping (v7-identical): 8 waves = 4 cout-q x 2 sp-halves ----
    const int lane  = t & 63;
    const int wv    = t >> 6;
    const int wq    = wv >> 1;
    const int wc    = wv & 1;
    const int frow  = lane & 31;
    const int khalf = lane >> 5;
    const size_t arow = (size_t)(wq * 32 + frow) * 8;
    const int bmask = ((frow >> 1) & 7) << 3;
    const int brw0  = (wc * 64 + frow) * LDC;
    const int brw1  = (wc * 64 + 32 + frow) * LDC;

    f32x16 acc[2];
#pragma unroll
    for (int j = 0; j < 2; j++)
#pragma unroll
        for (int e = 0; e < 16; e++) acc[j][e] = 0.f;

    f4u G[8];
    f16x8 aA[4], aB[4];

    // 8 float4 gathers for kernel-row R: cols ow..ow+3 of input row oh+R
#define GATHER4(R)                                                             \
    {                                                                          \
        _Pragma("unroll")                                                      \
        for (int j = 0; j < 8; j++)                                            \
            G[j] = *reinterpret_cast<const f4u*>(Xr + (size_t)j * CH_STRIDE + (R) * W); \
    }

    // convert G -> 3 shift-slots: sp0 val = G.v[kw], sp1 val = G.v[kw+1]
#define CVTROW()                                                               \
    {                                                                          \
        _Pragma("unroll")                                                      \
        for (int sh = 0; sh < 3; sh++) {                                       \
            union { uint u[4]; f16x8 v; } px, py;                              \
            _Pragma("unroll")                                                  \
            for (int p = 0; p < 4; p++) {                                      \
                px.u[p] = pkrtz_u32(G[2 * p].v[sh],     G[2 * p + 1].v[sh]);   \
                py.u[p] = pkrtz_u32(G[2 * p].v[sh + 1], G[2 * p + 1].v[sh + 1]); \
            }                                                                  \
            *reinterpret_cast<f16x8*>(&Bs[sh][whw0]) = px.v;                   \
            *reinterpret_cast<f16x8*>(&Bs[sh][whw1]) = py.v;                   \
        }                                                                      \
    }

#define ALOAD(DST, S)                                                          \
    {                                                                          \
        _Pragma("unroll")                                                      \
        for (int kk = 0; kk < 4; kk++)                                         \
            DST[kk] = *reinterpret_cast<const f16x8*>(                         \
                &A16[(size_t)(((S) * 8 + kk * 2 + khalf) * COUT) * 8 + arow]); \
    }

#define MFMA_SH(SH, AREG)                                                      \
    {                                                                          \
        _Pragma("unroll")                                                      \
        for (int kk = 0; kk < 4; kk++) {                                       \
            const int chw = (kk * 16 + khalf * 8) ^ bmask;                     \
            f16x8 b0 = *reinterpret_cast<const f16x8*>(&Bs[SH][brw0 + chw]);   \
            f16x8 b1 = *reinterpret_cast<const f16x8*>(&Bs[SH][brw1 + chw]);   \
            acc[0] = __builtin_amdgcn_mfma_f32_32x32x16_f16(AREG[kk], b0, acc[0], 0, 0, 0); \
            acc[1] = __builtin_amdgcn_mfma_f32_32x32x16_f16(AREG[kk], b1, acc[1], 0, 0, 0); \
        }                                                                      \
    }

    // ---- prologue ----
    GATHER4(0);
    ALOAD(aA, 0);

    // ---- Row 0 (shifts 0,1,2) ----
    CVTROW();
    __syncthreads();                  // RAW: Bs ready
    GATHER4(1);                       // next row's X, overlaps MFMA
    ALOAD(aB, 1);
    MFMA_SH(0, aA);
    ALOAD(aA, 2);
    MFMA_SH(1, aB);
    ALOAD(aB, 3);
    MFMA_SH(2, aA);
    __syncthreads();                  // WAR: all reads done before overwrite

    // ---- Row 1 (shifts 3,4,5) ----
    CVTROW();
    __syncthreads();
    GATHER4(2);
    ALOAD(aA, 4);
    MFMA_SH(0, aB);
    ALOAD(aB, 5);
    MFMA_SH(1, aA);
    ALOAD(aA, 6);
    MFMA_SH(2, aB);
    __syncthreads();

    // ---- Row 2 (shifts 6,7,8) ----
    CVTROW();
    __syncthreads();
    ALOAD(aB, 7);
    MFMA_SH(0, aA);
    ALOAD(aA, 8);
    MFMA_SH(1, aB);
    MFMA_SH(2, aA);

#undef GATHER4
#undef CVTROW
#undef ALOAD
#undef MFMA_SH

    // ---- store (v3-verified): D col=frow(sp), cout row=(reg&3)+8*(reg>>2)+4*khalf ----
#pragma unroll
    for (int j = 0; j < 2; j++) {
        const int sp2 = spBase + wc * 64 + j * 32 + frow;
        const int n2  = sp2 / OSP;
        const int r2  = sp2 - n2 * OSP;
        float* Ob = Out + (size_t)n2 * (COUT * (size_t)OSP) + r2;
        const int cbase = wq * 32 + 4 * khalf;
#pragma unroll
        for (int reg = 0; reg < 16; reg++) {
            const int crow = cbase + (reg & 3) + 8 * (reg >> 2);
            Ob[(size_t)crow * OSP] = acc[j][reg];
        }
    }
}

extern "C" void kernel_launch(void* const* d_in, const int* in_sizes, int n_in,
                              void* d_out, int out_size, void* d_ws, size_t ws_size,
                              hipStream_t stream) {
    const float* X  = (const float*)d_in[0];
    const float* Kw = (const float*)d_in[1];
    float* Out = (float*)d_out;
    _Float16* A16 = (_Float16*)d_ws;    // 147456 B

    prep_a<<<(COUT * KTOT + 255) / 256, 256, 0, stream>>>(Kw, A16);
    conv_v11<<<SPTOT / 128, 512, 0, stream>>>(X, A16, Out);
}

// Round 18
// 122.512 us; speedup vs baseline: 1.0056x; 1.0056x over previous
//
#include <hip/hip_runtime.h>

// Conv2d 3x3 VALID (NCHW/OIHW, fp32), fp16 MFMA, v12 "lean step".
// prep_x: X fp32 -> X16t[n][h][w][c] fp16 in ws (LDS-transposed, coalesced).
// main: B staged via 2x global_load_lds dwordx4 per thread per step; bank
// swizzle baked into per-lane SOURCE addr (LDS linear, m173 pattern); per-step
// source offset = compile-time (kh*112+kw)*64. No gathers/cvt/ds_write in main.
// v7-verified mappings, A reg ping-pong, __syncthreads, bit-identical math.

typedef __attribute__((ext_vector_type(8)))  _Float16 f16x8;
typedef __attribute__((ext_vector_type(16))) float    f32x16;

typedef __attribute__((address_space(3))) uint       lds_u32;
typedef __attribute__((address_space(1))) const uint glb_u32;

constexpr int C_IN = 64, H = 112, W = 112;
constexpr int COUT = 128, OH = 110, OW = 110;
constexpr int NIMG = 32;
constexpr int KTOT = C_IN * 9;            // 576
constexpr int OSP  = OH * OW;             // 12100
constexpr int SPTOT = NIMG * OSP;         // 387200 = 3025*128
constexpr int IMG_STRIDE = C_IN * H * W;
constexpr int CH_STRIDE  = H * W;         // 12544
constexpr size_t A16_BYTES = (size_t)KTOT * COUT * 2;     // 147456
// X16t: [n][h][w][c] fp16 = 32*112*112*64*2 = 51,380,224 B (needs ws >= ~51.6MB)

__device__ __forceinline__ uint pkrtz_u32(float lo, float hi) {
    union { __fp16 __attribute__((ext_vector_type(2))) h; uint u; } c;
    c.h = __builtin_amdgcn_cvt_pkrtz(lo, hi);
    return c.u;
}

// A16[((s*8+o)*COUT + cout)*8 + j] = (f16)Kw[cout][(o*8+j)*9 + s]  (v4-verified)
__global__ void prep_a(const float* __restrict__ Kw, _Float16* __restrict__ A16) {
    int idx = blockIdx.x * 256 + threadIdx.x;
    if (idx >= COUT * KTOT) return;
    int cout = idx / KTOT, k = idx - cout * KTOT;
    int c = k / 9, s = k - c * 9;
    int o = c >> 3, j = c & 7;
    A16[((size_t)(s * 8 + o) * COUT + cout) * 8 + j] = (_Float16)Kw[idx];
}

// X16t[n][h][w][c] = (f16)X[n][c][h][w].  One block per (n,h) row; LDS transpose.
__global__ __launch_bounds__(256, 4)
void prep_x(const float* __restrict__ X, _Float16* __restrict__ X16t) {
    __shared__ _Float16 L[W * 72];            // [w][c], c padded to 72
    const int t = threadIdx.x;
    const int n = blockIdx.x / H, h = blockIdx.x - n * H;
    const float* src = X + (size_t)n * IMG_STRIDE + (size_t)h * W;
    const int c = t >> 2, q = t & 3;          // 4 threads per channel, 28 w each
    const float* sc = src + (size_t)c * CH_STRIDE + q * 28;
#pragma unroll
    for (int v = 0; v < 7; v++) {
        float4 f = *reinterpret_cast<const float4*>(sc + v * 4);
        const int w0 = q * 28 + v * 4;
        L[(w0 + 0) * 72 + c] = (_Float16)f.x;
        L[(w0 + 1) * 72 + c] = (_Float16)f.y;
        L[(w0 + 2) * 72 + c] = (_Float16)f.z;
        L[(w0 + 3) * 72 + c] = (_Float16)f.w;
    }
    __syncthreads();
    _Float16* dst = X16t + ((size_t)n * H + h) * W * 64;  // 896 x 16B units
#pragma unroll
    for (int r = 0; r < 4; r++) {
        const int u = r * 256 + t;
        if (u < 896) {
            const int w = u >> 3, sl = u & 7;
            *reinterpret_cast<f16x8*>(dst + (size_t)u * 8) =
                *reinterpret_cast<const f16x8*>(&L[w * 72 + sl * 8]);
        }
    }
}

__global__ __launch_bounds__(512, 4)
void conv_v12(const _Float16* __restrict__ X16t,
              const _Float16* __restrict__ A16,
              float* __restrict__ Out)
{
    __shared__ __align__(16) _Float16 Bs[2][128 * 64];   // 2 x 16 KB

    const int t = threadIdx.x;

    // XCD-bijective block swizzle (m204); nwg=3025
    const int nwg = gridDim.x;
    const int q8 = nwg >> 3, r8 = nwg & 7;
    const int xcd = blockIdx.x & 7, idx8 = blockIdx.x >> 3;
    const int bid = (xcd < r8 ? xcd * (q8 + 1) : r8 * (q8 + 1) + (xcd - r8) * q8) + idx8;
    const int spBase = bid * 128;

    // ---- staging: 2 x 16B units/thread; unit u -> sp=u>>3, slot=u&7.
    //      gld_lds dest lane-linear; SOURCE carries swizzle oct = slot^(sp&7).
    const int lane = t & 63;
    const int wv   = t >> 6;
    const int u0 = wv * 128 + lane;
    const int u1 = u0 + 64;
    const _Float16* s0;
    const _Float16* s1;
    {
        const int uu[2] = {u0, u1};
        const _Float16* ss[2];
#pragma unroll
        for (int i = 0; i < 2; i++) {
            const int u  = uu[i];
            const int sp = u >> 3, slot = u & 7;
            const int spg = spBase + sp;
            const int n   = spg / OSP;
            const int r   = spg - n * OSP;
            const int oh  = r / OW;
            const int ow  = r - oh * OW;
            ss[i] = X16t + (((size_t)n * H + oh) * W + ow) * 64 + (slot ^ (sp & 7)) * 8;
        }
        s0 = ss[0]; s1 = ss[1];
    }
    const int l0 = u0 * 8;   // fp16 index in Bs buffer (lane-linear x16B)
    const int l1 = u1 * 8;

    // ---- compute mapping (v7-identical): 8 waves = 4 cout-q x 2 sp-halves ----
    const int wq    = wv >> 1;
    const int wc    = wv & 1;
    const int frow  = lane & 31;
    const int khalf = lane >> 5;
    const size_t arow = (size_t)(wq * 32 + frow) * 8;
    const int bmask = frow & 7;                  // row&7 (rows 32 apart share it)
    const int brw0  = (wc * 64 + frow) * 64;
    const int brw1  = brw0 + 32 * 64;

    f32x16 acc[2];
#pragma unroll
    for (int j = 0; j < 2; j++)
#pragma unroll
        for (int e = 0; e < 16; e++) acc[j][e] = 0.f;

    f16x8 aA[4], aB[4];

#define SOFFC(S) ((((S) / 3) * W + ((S) % 3)) * 64)

#define STAGE(S, B)                                                            \
    {                                                                          \
        __builtin_amdgcn_global_load_lds((const glb_u32*)(s0 + SOFFC(S)),      \
                                         (lds_u32*)(&Bs[B][l0]), 16, 0, 0);    \
        __builtin_amdgcn_global_load_lds((const glb_u32*)(s1 + SOFFC(S)),      \
                                         (lds_u32*)(&Bs[B][l1]), 16, 0, 0);    \
    }

#define ALOAD(DST, S)                                                          \
    {                                                                          \
        _Pragma("unroll")                                                      \
        for (int kk = 0; kk < 4; kk++)                                         \
            DST[kk] = *reinterpret_cast<const f16x8*>(                         \
                &A16[(size_t)(((S) * 8 + kk * 2 + khalf) * COUT) * 8 + arow]); \
    }

#define MFMA_STEP(B, AREG)                                                     \
    {                                                                          \
        _Pragma("unroll")                                                      \
        for (int kk = 0; kk < 4; kk++) {                                       \
            const int slot = ((kk * 2 + khalf) ^ bmask) * 8;                   \
            f16x8 b0 = *reinterpret_cast<const f16x8*>(&Bs[B][brw0 + slot]);   \
            f16x8 b1 = *reinterpret_cast<const f16x8*>(&Bs[B][brw1 + slot]);   \
            acc[0] = __builtin_amdgcn_mfma_f32_32x32x16_f16(AREG[kk], b0, acc[0], 0, 0, 0); \
            acc[1] = __builtin_amdgcn_mfma_f32_32x32x16_f16(AREG[kk], b1, acc[1], 0, 0, 0); \
        }                                                                      \
    }

#define STEP(S, CUR, NXT)                                                      \
    {                                                                          \
        ALOAD(NXT, (S) + 1);                                                   \
        STAGE((S) + 1, ((S) + 1) & 1);                                         \
        MFMA_STEP((S) & 1, CUR);                                               \
        __syncthreads();                                                       \
    }

    // ---- prologue: A(0) + B(0) staged ----
    ALOAD(aA, 0);
    STAGE(0, 0);
    __syncthreads();

    STEP(0, aA, aB);
    STEP(1, aB, aA);
    STEP(2, aA, aB);
    STEP(3, aB, aA);
    STEP(4, aA, aB);
    STEP(5, aB, aA);
    STEP(6, aA, aB);
    STEP(7, aB, aA);
    MFMA_STEP(0, aA);   // s=8 in buf0

#undef STAGE
#undef ALOAD
#undef MFMA_STEP
#undef STEP
#undef SOFFC

    // ---- store (v3-verified): D col=frow(sp), cout row=(reg&3)+8*(reg>>2)+4*khalf ----
#pragma unroll
    for (int j = 0; j < 2; j++) {
        const int sp2 = spBase + wc * 64 + j * 32 + frow;
        const int n2  = sp2 / OSP;
        const int r2  = sp2 - n2 * OSP;
        float* Ob = Out + (size_t)n2 * (COUT * (size_t)OSP) + r2;
        const int cbase = wq * 32 + 4 * khalf;
#pragma unroll
        for (int reg = 0; reg < 16; reg++) {
            const int crow = cbase + (reg & 3) + 8 * (reg >> 2);
            Ob[(size_t)crow * OSP] = acc[j][reg];
        }
    }
}

extern "C" void kernel_launch(void* const* d_in, const int* in_sizes, int n_in,
                              void* d_out, int out_size, void* d_ws, size_t ws_size,
                              hipStream_t stream) {
    const float* X  = (const float*)d_in[0];
    const float* Kw = (const float*)d_in[1];
    float* Out = (float*)d_out;
    _Float16* A16  = (_Float16*)d_ws;
    _Float16* X16t = (_Float16*)((char*)d_ws + A16_BYTES);   // needs ~51.6 MB ws

    prep_a<<<(COUT * KTOT + 255) / 256, 256, 0, stream>>>(Kw, A16);
    prep_x<<<NIMG * H, 256, 0, stream>>>(X, X16t);
    conv_v12<<<SPTOT / 128, 512, 0, stream>>>(X16t, A16, Out);
}

// Round 19
// 118.840 us; speedup vs baseline: 1.0367x; 1.0309x over previous
//
#include <hip/hip_runtime.h>

// Conv2d 3x3 VALID (NCHW/OIHW, fp32), fp16 MFMA, v13 "row-granular lean steps".
// prep_x: X -> X16t[n][h][w][c] fp16 (unchanged from v12).
// main: per kernel-row kh, the 3 kw-shifts over a 128-sp tile need ONE
// contiguous X16t segment (<=134 slots of 64ch; OW=110 vs W=112 makes row
// jumps +2-halo contiguous). Stage 136 slots (17KB) via global_load_lds once
// per row: 3 staging rounds + 4 barriers total (was 9/10), gld_lds 18->7.
// Reads use slot windex(sp)+kw with source-baked XOR swizzle (m173 pattern).
// A ping-pong, MFMA order s=0..8, store: unchanged -> bit-identical output.

typedef __attribute__((ext_vector_type(8)))  _Float16 f16x8;
typedef __attribute__((ext_vector_type(16))) float    f32x16;

typedef __attribute__((address_space(3))) uint       lds_u32;
typedef __attribute__((address_space(1))) const uint glb_u32;

constexpr int C_IN = 64, H = 112, W = 112;
constexpr int COUT = 128, OH = 110, OW = 110;
constexpr int NIMG = 32;
constexpr int KTOT = C_IN * 9;            // 576
constexpr int OSP  = OH * OW;             // 12100
constexpr int SPTOT = NIMG * OSP;         // 387200 = 3025*128
constexpr int IMG_STRIDE = C_IN * H * W;
constexpr int CH_STRIDE  = H * W;         // 12544
constexpr int XROW = W * C_IN;            // 7168 fp16 per X16t row
constexpr int SLOTS = 136;                // staged w-slots per kernel row (need <=134)
constexpr int UNITS = SLOTS * 8;          // 1088 16B-units
constexpr size_t A16_BYTES = (size_t)KTOT * COUT * 2;     // 147456

__device__ __forceinline__ uint pkrtz_u32(float lo, float hi) {
    union { __fp16 __attribute__((ext_vector_type(2))) h; uint u; } c;
    c.h = __builtin_amdgcn_cvt_pkrtz(lo, hi);
    return c.u;
}

// A16[((s*8+o)*COUT + cout)*8 + j] = (f16)Kw[cout][(o*8+j)*9 + s]  (v4-verified)
__global__ void prep_a(const float* __restrict__ Kw, _Float16* __restrict__ A16) {
    int idx = blockIdx.x * 256 + threadIdx.x;
    if (idx >= COUT * KTOT) return;
    int cout = idx / KTOT, k = idx - cout * KTOT;
    int c = k / 9, s = k - c * 9;
    int o = c >> 3, j = c & 7;
    A16[((size_t)(s * 8 + o) * COUT + cout) * 8 + j] = (_Float16)Kw[idx];
}

// X16t[n][h][w][c] = (f16)X[n][c][h][w]  (v12-verified, LDS transpose)
__global__ __launch_bounds__(256, 4)
void prep_x(const float* __restrict__ X, _Float16* __restrict__ X16t) {
    __shared__ _Float16 L[W * 72];
    const int t = threadIdx.x;
    const int n = blockIdx.x / H, h = blockIdx.x - n * H;
    const float* src = X + (size_t)n * IMG_STRIDE + (size_t)h * W;
    const int c = t >> 2, q = t & 3;
    const float* sc = src + (size_t)c * CH_STRIDE + q * 28;
#pragma unroll
    for (int v = 0; v < 7; v++) {
        float4 f = *reinterpret_cast<const float4*>(sc + v * 4);
        const int w0 = q * 28 + v * 4;
        L[(w0 + 0) * 72 + c] = (_Float16)f.x;
        L[(w0 + 1) * 72 + c] = (_Float16)f.y;
        L[(w0 + 2) * 72 + c] = (_Float16)f.z;
        L[(w0 + 3) * 72 + c] = (_Float16)f.w;
    }
    __syncthreads();
    _Float16* dst = X16t + ((size_t)n * H + h) * XROW;
#pragma unroll
    for (int r = 0; r < 4; r++) {
        const int u = r * 256 + t;
        if (u < 896) {
            const int w = u >> 3, sl = u & 7;
            *reinterpret_cast<f16x8*>(dst + (size_t)u * 8) =
                *reinterpret_cast<const f16x8*>(&L[w * 72 + sl * 8]);
        }
    }
}

__global__ __launch_bounds__(512, 4)
void conv_v13(const _Float16* __restrict__ X16t,
              const _Float16* __restrict__ A16,
              float* __restrict__ Out)
{
    __shared__ __align__(16) _Float16 Bs[2][SLOTS * 64];   // 2 x 17408 B

    const int t = threadIdx.x;

    // XCD-bijective block swizzle (m204); nwg=3025
    const int nwg = gridDim.x;
    const int q8 = nwg >> 3, r8 = nwg & 7;
    const int xcd = blockIdx.x & 7, idx8 = blockIdx.x >> 3;
    const int bid = (xcd < r8 ? xcd * (q8 + 1) : r8 * (q8 + 1) + (xcd - r8) * q8) + idx8;
    const int spBase = bid * 128;

    const int n0  = spBase / OSP;
    const int r0  = spBase - n0 * OSP;
    const int oh0 = r0 / OW;
    const int ow0 = r0 - oh0 * OW;
    // slots [0,seg1len) come from image n0 linearly from (oh0,ow0);
    // slots >= seg1len from image n0+1 starting at (0,0). (2-halo contiguity)
    const int seg1len = (109 - oh0) * 112 + (112 - ow0);

    // ---- staging: units u0=t, u1=t+512, u2=1024+t (wave0 only) ----
    const int lane = t & 63;
    const int wv   = t >> 6;
    const _Float16* sU0;
    const _Float16* sU1;
    const _Float16* sU2;
    {
        const int uu[3] = {t, t + 512, 1024 + (t & 63)};
        const _Float16* ss[3];
#pragma unroll
        for (int i = 0; i < 3; i++) {
            const int u  = uu[i];
            const int ws = u >> 3, oct = u & 7;
            const int so = (oct ^ (ws & 7)) * 8;
            size_t lin;
            if (ws < seg1len) {
                lin = (size_t)n0 * CH_STRIDE + (size_t)(oh0 * 112 + ow0 + ws);
            } else {
                const int nn = (n0 < NIMG - 1) ? n0 + 1 : n0;   // clamp: pad units never read
                lin = (size_t)nn * CH_STRIDE + (size_t)(ws - seg1len);
            }
            ss[i] = X16t + lin * 64 + so;
        }
        sU0 = ss[0]; sU1 = ss[1]; sU2 = ss[2];
    }

    // ---- compute mapping (v7/v12): 8 waves = 4 cout-q x 2 sp-halves ----
    const int wq    = wv >> 1;
    const int wc    = wv & 1;
    const int frow  = lane & 31;
    const int khalf = lane >> 5;
    const size_t arow = (size_t)(wq * 32 + frow) * 8;

    // per-lane B slot indices for its two sp rows
    int w0i, w1i;
    {
        const int ii[2] = {wc * 64 + frow, wc * 64 + 32 + frow};
        int wx[2];
#pragma unroll
        for (int i = 0; i < 2; i++) {
            const int spg = spBase + ii[i];
            const int n   = spg / OSP;
            const int r   = spg - n * OSP;
            const int oh  = r / OW;
            const int ow  = r - oh * OW;
            wx[i] = (n == n0) ? (oh - oh0) * 112 + (ow - ow0)
                              : seg1len + oh * 112 + ow;
        }
        w0i = wx[0]; w1i = wx[1];
    }

    f32x16 acc[2];
#pragma unroll
    for (int j = 0; j < 2; j++)
#pragma unroll
        for (int e = 0; e < 16; e++) acc[j][e] = 0.f;

    f16x8 aA[4], aB[4];

    // stage kernel-row R: add R*XROW to each unit source (rows shift inside image)
#define STAGE(R, B)                                                            \
    {                                                                          \
        __builtin_amdgcn_global_load_lds((const glb_u32*)(sU0 + (R) * XROW),   \
            (lds_u32*)(&Bs[B][(size_t)t * 8]), 16, 0, 0);                      \
        __builtin_amdgcn_global_load_lds((const glb_u32*)(sU1 + (R) * XROW),   \
            (lds_u32*)(&Bs[B][(size_t)(t + 512) * 8]), 16, 0, 0);              \
        if (wv == 0)                                                           \
            __builtin_amdgcn_global_load_lds((const glb_u32*)(sU2 + (R) * XROW), \
                (lds_u32*)(&Bs[B][(size_t)(1024 + lane) * 8]), 16, 0, 0);      \
    }

#define ALOAD(DST, S)                                                          \
    {                                                                          \
        _Pragma("unroll")                                                      \
        for (int kk = 0; kk < 4; kk++)                                         \
            DST[kk] = *reinterpret_cast<const f16x8*>(                         \
                &A16[(size_t)(((S) * 8 + kk * 2 + khalf) * COUT) * 8 + arow]); \
    }

#define MFMA_SH(KW, B, AREG)                                                   \
    {                                                                          \
        const int sa = w0i + (KW);                                             \
        const int sb = w1i + (KW);                                             \
        _Pragma("unroll")                                                      \
        for (int kk = 0; kk < 4; kk++) {                                       \
            const int oct = kk * 2 + khalf;                                    \
            f16x8 b0 = *reinterpret_cast<const f16x8*>(                        \
                &Bs[B][sa * 64 + ((oct ^ (sa & 7)) << 3)]);                    \
            f16x8 b1 = *reinterpret_cast<const f16x8*>(                        \
                &Bs[B][sb * 64 + ((oct ^ (sb & 7)) << 3)]);                    \
            acc[0] = __builtin_amdgcn_mfma_f32_32x32x16_f16(AREG[kk], b0, acc[0], 0, 0, 0); \
            acc[1] = __builtin_amdgcn_mfma_f32_32x32x16_f16(AREG[kk], b1, acc[1], 0, 0, 0); \
        }                                                                      \
    }

    // ---- prologue: row0 -> buf0 ----
    ALOAD(aA, 0);
    STAGE(0, 0);
    __syncthreads();

    // ---- R=0 (shifts 0,1,2 from buf0), stage row1 -> buf1 ----
    STAGE(1, 1);
    ALOAD(aB, 1); MFMA_SH(0, 0, aA);
    ALOAD(aA, 2); MFMA_SH(1, 0, aB);
    ALOAD(aB, 3); MFMA_SH(2, 0, aA);
    __syncthreads();

    // ---- R=1 (shifts 3,4,5 from buf1), stage row2 -> buf0 ----
    STAGE(2, 0);
    ALOAD(aA, 4); MFMA_SH(0, 1, aB);
    ALOAD(aB, 5); MFMA_SH(1, 1, aA);
    ALOAD(aA, 6); MFMA_SH(2, 1, aB);
    __syncthreads();

    // ---- R=2 (shifts 6,7,8 from buf0) ----
    ALOAD(aB, 7); MFMA_SH(0, 0, aA);
    ALOAD(aA, 8); MFMA_SH(1, 0, aB);
    MFMA_SH(2, 0, aA);

#undef STAGE
#undef ALOAD
#undef MFMA_SH

    // ---- store (v3-verified): D col=frow(sp), cout row=(reg&3)+8*(reg>>2)+4*khalf ----
#pragma unroll
    for (int j = 0; j < 2; j++) {
        const int sp2 = spBase + wc * 64 + j * 32 + frow;
        const int n2  = sp2 / OSP;
        const int r2  = sp2 - n2 * OSP;
        float* Ob = Out + (size_t)n2 * (COUT * (size_t)OSP) + r2;
        const int cbase = wq * 32 + 4 * khalf;
#pragma unroll
        for (int reg = 0; reg < 16; reg++) {
            const int crow = cbase + (reg & 3) + 8 * (reg >> 2);
            Ob[(size_t)crow * OSP] = acc[j][reg];
        }
    }
}

extern "C" void kernel_launch(void* const* d_in, const int* in_sizes, int n_in,
                              void* d_out, int out_size, void* d_ws, size_t ws_size,
                              hipStream_t stream) {
    const float* X  = (const float*)d_in[0];
    const float* Kw = (const float*)d_in[1];
    float* Out = (float*)d_out;
    _Float16* A16  = (_Float16*)d_ws;
    _Float16* X16t = (_Float16*)((char*)d_ws + A16_BYTES);   // ~51.6 MB total ws

    prep_a<<<(COUT * KTOT + 255) / 256, 256, 0, stream>>>(Kw, A16);
    prep_x<<<NIMG * H, 256, 0, stream>>>(X, X16t);
    conv_v13<<<SPTOT / 128, 512, 0, stream>>>(X16t, A16, Out);
}